// Round 14
// baseline (155.776 us; speedup 1.0000x reference)
//
#include <hip/hip_runtime.h>

// KMeans soft-assignment via bf16 hi/lo split MFMA (3 passes), fused softmax.
// logits = (2*x.c - ||c||^2)/T, T=0.1; ||x||^2 cancels in softmax.
// R24: ANTI-CONVOY STAGGER on R20 (best, 46.3us). R22/R23 ring epilogue
// spilled (3rd confirmation: register file exactly full at BM=128; any
// extra liveness spills into the K-loop). Remaining untested mechanism
// consistent with ALL data: wave convoying -- 2 waves/SIMD run identical
// streams from the same barrier -> phase-locked: both ds_read together
// (R-phase doubles), both MFMA together (queue serializes) -> chunk time
// ~ R+M serial (3.1k+3.7k cyc) not max(R,M). Evidence: every lockstep-
// increasing change (R18 sub-barriers, R16 phases) regressed; least-
// synchronized kernels are best. Fix (0 regs, 0 sync): stagger group
// order per wave -- ph=(w^(w>>2))&1 (differs within SIMD-pair under
// either w%4 or w/2 mapping); ph=0: groups 0,1,2,3; ph=1: 2,3,0,1.
// Wave-uniform branch, fully static bodies. Per-acc pass order and chunk
// order unchanged -> bit-identical (absmax 0.00390625). Everything else
// = R20 verbatim: counted vmcnt(4) -> s_barrier -> DMA-after-barrier,
// pass-major MFMA, transpose epilogue.
// x: [32768,256] f32, c: [512,256] f32, out: [32768,512] f32
#define NROWS 32768
#define KC 512
#define DDIM 256
#define BM 128
#define BK 32
#define KCH (DDIM / BK)        // 8 k-chunks
#define CHUNK_USH (KC * BK)    // 16384 ushorts = 32 KB per chunk table

typedef __attribute__((ext_vector_type(8))) short bf16x8;
typedef __attribute__((ext_vector_type(4))) float f32x4;

union U8 { unsigned short u[8]; bf16x8 v; };

__device__ __forceinline__ unsigned short f2bf(float f) {   // RNE f32->bf16
    union { float f; unsigned int u; } a; a.f = f;
    unsigned int r = a.u + 0x7fffu + ((a.u >> 16) & 1u);
    return (unsigned short)(r >> 16);
}
__device__ __forceinline__ float bf2f(unsigned short h) {
    union { unsigned int u; float f; } a; a.u = ((unsigned int)h) << 16;
    return a.f;
}
// async global->LDS, 16B/lane; LDS dst must be wave-uniform base + lane*16
__device__ __forceinline__ void ld16(const void* g, void* l) {
    __builtin_amdgcn_global_load_lds(
        (const __attribute__((address_space(1))) unsigned int*)g,
        (__attribute__((address_space(3))) unsigned int*)l, 16, 0, 0);
}

// ---- prep: c -> chunk-major, LDS-swizzle-baked bf16 hi/lo + csq10 ----
// octet (col n, quad q) at chunk offset (n*4 + (q ^ ((n>>1)&3)))*8 ushorts
__global__ __launch_bounds__(64) void prep_c(const float* __restrict__ c,
                                             unsigned short* __restrict__ bhi,
                                             unsigned short* __restrict__ blo,
                                             float* __restrict__ csq10) {
    const int n = blockIdx.x, lane = threadIdx.x;
    const int d0 = lane * 4;
    float4 v = ((const float4*)(c + (size_t)n * DDIM))[lane];
    float vv[4] = {v.x, v.y, v.z, v.w};
    unsigned short hh[4], ll[4];
    float ssq = 0.f;
    #pragma unroll
    for (int i = 0; i < 4; ++i) {
        ssq += vv[i] * vv[i];
        hh[i] = f2bf(vv[i]);
        ll[i] = f2bf(vv[i] - bf2f(hh[i]));
    }
    #pragma unroll
    for (int off = 32; off; off >>= 1) ssq += __shfl_xor(ssq, off);
    if (lane == 0) csq10[n] = 10.f * ssq;
    const int ks = d0 >> 5;
    const int q  = (d0 >> 3) & 3;
    const int s  = q ^ ((n >> 1) & 3);
    const size_t dst = (size_t)ks * CHUNK_USH + (n * 4 + s) * 8 + (d0 & 7);
    *(ushort4*)(bhi + dst) = make_ushort4(hh[0], hh[1], hh[2], hh[3]);
    *(ushort4*)(blo + dst) = make_ushort4(ll[0], ll[1], ll[2], ll[3]);
}

// ---- main: 256 blocks x 512 threads (8 waves = 4 M-groups x 2 N-halves) ----
union SmemU {
    struct { unsigned short Bh[2][CHUNK_USH], Bl[2][CHUNK_USH]; } k;  // 128 KB
    float lbuf[32 * 516];                                             // 66 KB overlay
};

__global__ __launch_bounds__(512, 2) void kmeans_mfma(
    const float* __restrict__ x, const unsigned short* __restrict__ bhi,
    const unsigned short* __restrict__ blo, const float* __restrict__ csq10,
    float* __restrict__ out) {
    __shared__ __align__(16) SmemU sm;
    __shared__ float red[2][2][BM];   // 2 KB

    const int tid  = threadIdx.x;
    const int w    = tid >> 6, lane = tid & 63;
    const int wm   = w >> 1, wn = w & 1;
    const int cc   = lane & 15, q = lane >> 4;
    const int row0 = blockIdx.x * BM;
    const int ph   = (w ^ (w >> 2)) & 1;   // anti-convoy phase key

    f32x4 acc[2][16];
    #pragma unroll
    for (int mt = 0; mt < 2; ++mt)
        #pragma unroll
        for (int t = 0; t < 16; ++t) acc[mt][t] = (f32x4){0.f, 0.f, 0.f, 0.f};

    // A: lane owns rows (row0 + wm*32 + mt*16 + cc), k-octet q*8 per chunk
    const float* xA0 = x + (size_t)(row0 + wm * 32 + cc) * DDIM + q * 8;
    const float* xA1 = xA0 + (size_t)16 * DDIM;
    // B fragment offset within staged chunk
    const int sF = q ^ ((cc >> 1) & 3);
    const int bF = (4 * cc + sF) * 8;       // + (wn*16+t)*512
    // DMA slots: wave w, j=0..3 -> 1 KB segment (w*4+j)*512 ushorts
    const int dmaOff = (w * 4) * 512;

    // ---- prologue: issue A(0), then DMA chunk 0 -> buf 0 (no barrier yet) ----
    float4 c00 = *(const float4*)xA0;
    float4 c01 = *(const float4*)(xA0 + 4);
    float4 c10 = *(const float4*)xA1;
    float4 c11 = *(const float4*)(xA1 + 4);
    #pragma unroll
    for (int j = 0; j < 4; ++j) {
        const int o = dmaOff + j * 512;
        ld16(bhi + o + lane * 8, &sm.k.Bh[0][o]);
        ld16(blo + o + lane * 8, &sm.k.Bl[0][o]);
    }

    #pragma unroll
    for (int ks = 0; ks < KCH; ++ks) {
        const int pp = ks & 1;
        // convert A(ks): compiler inserts a COUNTED vmcnt for these regs
        // (DMA(ks)'s 8 ops are younger -> stay in flight)
        bf16x8 ah[2], al[2];
        {
            float v0[8] = {c00.x, c00.y, c00.z, c00.w, c01.x, c01.y, c01.z, c01.w};
            float v1[8] = {c10.x, c10.y, c10.z, c10.w, c11.x, c11.y, c11.z, c11.w};
            U8 H0, L0, H1, L1;
            #pragma unroll
            for (int e = 0; e < 8; ++e) {
                H0.u[e] = f2bf(v0[e]); L0.u[e] = f2bf(v0[e] - bf2f(H0.u[e]));
                H1.u[e] = f2bf(v1[e]); L1.u[e] = f2bf(v1[e] - bf2f(H1.u[e]));
            }
            ah[0] = H0.v; al[0] = L0.v; ah[1] = H1.v; al[1] = L1.v;
        }
        // issue A(ks+1) raw (youngest; stays in flight across the barrier)
        float4 n00, n01, n10, n11;
        if (ks < KCH - 1) {
            const int kn = (ks + 1) * BK;
            n00 = *(const float4*)(xA0 + kn);
            n01 = *(const float4*)(xA0 + kn + 4);
            n10 = *(const float4*)(xA1 + kn);
            n11 = *(const float4*)(xA1 + kn + 4);
        }
        __builtin_amdgcn_sched_barrier(0);
        // counted wait: DMA(ks) complete; A(ks+1) (4 youngest) stays in flight.
        if (ks < KCH - 1) {
            asm volatile("s_waitcnt vmcnt(4)" ::: "memory");
        } else {
            asm volatile("s_waitcnt vmcnt(0)" ::: "memory");
        }
        __builtin_amdgcn_s_barrier();
        __builtin_amdgcn_sched_barrier(0);
        // issue DMA(ks+1) into the other slot (safe only post-barrier:
        // chunk ks-1's readers consumed that slot before this barrier)
        if (ks < KCH - 1) {
            const size_t cb = (size_t)(ks + 1) * CHUNK_USH;
            #pragma unroll
            for (int j = 0; j < 4; ++j) {
                const int o = dmaOff + j * 512;
                ld16(bhi + cb + o + lane * 8, &sm.k.Bh[1 - pp][o]);
                ld16(blo + cb + o + lane * 8, &sm.k.Bl[1 - pp][o]);
            }
        }
        // MFMA phase: 4 groups of 4 tiles, pass-major within group (R20).
        // ANTI-CONVOY: ph=1 waves run groups 2,3,0,1 so the co-resident
        // wave on the SIMD reads LDS while this one MFMAs, and vice versa.
        // Per-acc accumulation order unchanged -> bit-identical.
        #define GRP_BODY(grp)                                                            \
        {                                                                                \
            bf16x8 bh[4], bl[4];                                                         \
            _Pragma("unroll")                                                            \
            for (int tt = 0; tt < 4; ++tt) {                                             \
                const int bo = (wn * 16 + (grp) * 4 + tt) * 512 + bF;                    \
                bh[tt] = *(const bf16x8*)&sm.k.Bh[pp][bo];                               \
                bl[tt] = *(const bf16x8*)&sm.k.Bl[pp][bo];                               \
            }                                                                            \
            _Pragma("unroll")                                                            \
            for (int tt = 0; tt < 4; ++tt) {                                             \
                const int t = (grp) * 4 + tt;                                            \
                acc[0][t] = __builtin_amdgcn_mfma_f32_16x16x32_bf16(ah[0], bh[tt], acc[0][t], 0, 0, 0); \
                acc[1][t] = __builtin_amdgcn_mfma_f32_16x16x32_bf16(ah[1], bh[tt], acc[1][t], 0, 0, 0); \
            }                                                                            \
            _Pragma("unroll")                                                            \
            for (int tt = 0; tt < 4; ++tt) {                                             \
                const int t = (grp) * 4 + tt;                                            \
                acc[0][t] = __builtin_amdgcn_mfma_f32_16x16x32_bf16(ah[0], bl[tt], acc[0][t], 0, 0, 0); \
                acc[1][t] = __builtin_amdgcn_mfma_f32_16x16x32_bf16(ah[1], bl[tt], acc[1][t], 0, 0, 0); \
            }                                                                            \
            _Pragma("unroll")                                                            \
            for (int tt = 0; tt < 4; ++tt) {                                             \
                const int t = (grp) * 4 + tt;                                            \
                acc[0][t] = __builtin_amdgcn_mfma_f32_16x16x32_bf16(al[0], bh[tt], acc[0][t], 0, 0, 0); \
                acc[1][t] = __builtin_amdgcn_mfma_f32_16x16x32_bf16(al[1], bh[tt], acc[1][t], 0, 0, 0); \
            }                                                                            \
        }
        if (ph == 0) {
            GRP_BODY(0) GRP_BODY(1) GRP_BODY(2) GRP_BODY(3)
        } else {
            GRP_BODY(2) GRP_BODY(3) GRP_BODY(0) GRP_BODY(1)
        }
        #undef GRP_BODY
        c00 = n00; c01 = n01; c10 = n10; c11 = n11;
    }

    // ---- softmax stats: reduce over t, then cc-lanes, then wn pair via LDS ----
    float csqv[16];
    #pragma unroll
    for (int t = 0; t < 16; ++t) csqv[t] = csq10[wn * 256 + t * 16 + cc];
    const int rb = wm * 32 + q * 4;   // + mt*16 + g
    float M[2][4], I[2][4];
    #pragma unroll
    for (int mt = 0; mt < 2; ++mt)
        #pragma unroll
        for (int g = 0; g < 4; ++g) {
            float pm = -1e30f;
            #pragma unroll
            for (int t = 0; t < 16; ++t) pm = fmaxf(pm, 20.f * acc[mt][t][g] - csqv[t]);
            #pragma unroll
            for (int off = 1; off < 16; off <<= 1) pm = fmaxf(pm, __shfl_xor(pm, off));
            if (cc == 0) red[0][wn][rb + mt * 16 + g] = pm;
            M[mt][g] = pm;
        }
    __syncthreads();
    #pragma unroll
    for (int mt = 0; mt < 2; ++mt)
        #pragma unroll
        for (int g = 0; g < 4; ++g) {
            M[mt][g] = fmaxf(M[mt][g], red[0][1 - wn][rb + mt * 16 + g]);
            float ps = 0.f;
            #pragma unroll
            for (int t = 0; t < 16; ++t) ps += __expf(20.f * acc[mt][t][g] - csqv[t] - M[mt][g]);
            #pragma unroll
            for (int off = 1; off < 16; off <<= 1) ps += __shfl_xor(ps, off);
            if (cc == 0) red[1][wn][rb + mt * 16 + g] = ps;
        }
    __syncthreads();
    #pragma unroll
    for (int mt = 0; mt < 2; ++mt)
        #pragma unroll
        for (int g = 0; g < 4; ++g)
            I[mt][g] = 1.f / (red[1][0][rb + mt * 16 + g] + red[1][1][rb + mt * 16 + g]);

    // ---- transpose epilogue: 4 passes of 32 rows through lbuf, dense stores ----
    #pragma unroll
    for (int p = 0; p < 4; ++p) {
        if (wm == p) {
            #pragma unroll
            for (int mt = 0; mt < 2; ++mt)
                #pragma unroll
                for (int g = 0; g < 4; ++g) {
                    const int   lr = mt * 16 + q * 4 + g;
                    const float mg = M[mt][g], ig = I[mt][g];
                    #pragma unroll
                    for (int t = 0; t < 16; ++t)
                        sm.lbuf[lr * 516 + wn * 256 + t * 16 + cc] =
                            __expf(20.f * acc[mt][t][g] - csqv[t] - mg) * ig;
                }
        }
        __syncthreads();
        #pragma unroll
        for (int j = 0; j < 8; ++j) {
            const int f    = j * 512 + tid;     // 0..4095 float4 slots
            const int lrow = f >> 7;            // 0..31
            const int c4   = f & 127;
            float4    v    = *(const float4*)&sm.lbuf[lrow * 516 + c4 * 4];
            *(float4*)(out + (size_t)(row0 + p * 32 + lrow) * KC + c4 * 4) = v;
        }
        __syncthreads();
    }
}

extern "C" void kernel_launch(void* const* d_in, const int* in_sizes, int n_in,
                              void* d_out, int out_size, void* d_ws, size_t ws_size,
                              hipStream_t stream) {
    const float* x   = (const float*)d_in[0];
    const float* c   = (const float*)d_in[1];
    float*       out = (float*)d_out;

    unsigned short* bhi   = (unsigned short*)d_ws;                 // 256 KB
    unsigned short* blo   = bhi + (size_t)KCH * CHUNK_USH;         // 256 KB
    float*          csq10 = (float*)(blo + (size_t)KCH * CHUNK_USH);  // 2 KB

    prep_c<<<KC, 64, 0, stream>>>(c, bhi, blo, csq10);
    kmeans_mfma<<<NROWS / BM, 512, 0, stream>>>(x, bhi, blo, csq10, out);
}

// Round 15
// 121.772 us; speedup vs baseline: 1.2792x; 1.2792x over previous
//
#include <hip/hip_runtime.h>

// KMeans soft-assignment via bf16 hi/lo split MFMA (3 passes), fused softmax.
// logits = (2*x.c - ||c||^2)/T, T=0.1; ||x||^2 cancels in softmax.
// R25: HYBRID B SOURCING on R20 (best, 46.3us). R24 spilled (4th proof the
// reg file is exactly full -- change must be register-neutral). Structure
// evidence: all-LDS B (R10/17/20: 47-48) and all-global B (R12: 50.5) both
// pin ~48; the hybrid was never tested. Per chunk each wave's 16 tiles:
// groups 0-1 (8 tiles) from LDS (lgkmcnt pipe), groups 2-3 (8 tiles)
// DIRECT from L2 (vmcnt pipe) at the same table offsets -- two memory
// pipes each carry half. Staged tables halve (64KB LDS, tiles {0-7,16-23}),
// DMA halves to 4 ops/wave (same vmcnt(4) arithmetic: 4 DMA + 4 A).
// Transient B regs unchanged (32) -> register-neutral. In-order vmcnt
// means g2's B-wait force-drains A(ks+1) early (~300cyc/chunk exposure,
// cover = barrier+DMA+g0+g1) -- small vs ~1.5k cyc/chunk LDS-pipe relief.
// Tile/pass/accumulation order unchanged -> bit-identical (0.00390625).
// x: [32768,256] f32, c: [512,256] f32, out: [32768,512] f32
#define NROWS 32768
#define KC 512
#define DDIM 256
#define BM 128
#define BK 32
#define KCH (DDIM / BK)        // 8 k-chunks
#define CHUNK_USH (KC * BK)    // 16384 ushorts = 32 KB per chunk table
#define HALF_USH 8192          // staged half-table (tiles 0-7, 16-23)

typedef __attribute__((ext_vector_type(8))) short bf16x8;
typedef __attribute__((ext_vector_type(4))) float f32x4;

union U8 { unsigned short u[8]; bf16x8 v; };

__device__ __forceinline__ unsigned short f2bf(float f) {   // RNE f32->bf16
    union { float f; unsigned int u; } a; a.f = f;
    unsigned int r = a.u + 0x7fffu + ((a.u >> 16) & 1u);
    return (unsigned short)(r >> 16);
}
__device__ __forceinline__ float bf2f(unsigned short h) {
    union { unsigned int u; float f; } a; a.u = ((unsigned int)h) << 16;
    return a.f;
}
// async global->LDS, 16B/lane; LDS dst must be wave-uniform base + lane*16
__device__ __forceinline__ void ld16(const void* g, void* l) {
    __builtin_amdgcn_global_load_lds(
        (const __attribute__((address_space(1))) unsigned int*)g,
        (__attribute__((address_space(3))) unsigned int*)l, 16, 0, 0);
}

// ---- prep: c -> chunk-major, LDS-swizzle-baked bf16 hi/lo + csq10 ----
// octet (col n, quad q) at chunk offset (n*4 + (q ^ ((n>>1)&3)))*8 ushorts
__global__ __launch_bounds__(64) void prep_c(const float* __restrict__ c,
                                             unsigned short* __restrict__ bhi,
                                             unsigned short* __restrict__ blo,
                                             float* __restrict__ csq10) {
    const int n = blockIdx.x, lane = threadIdx.x;
    const int d0 = lane * 4;
    float4 v = ((const float4*)(c + (size_t)n * DDIM))[lane];
    float vv[4] = {v.x, v.y, v.z, v.w};
    unsigned short hh[4], ll[4];
    float ssq = 0.f;
    #pragma unroll
    for (int i = 0; i < 4; ++i) {
        ssq += vv[i] * vv[i];
        hh[i] = f2bf(vv[i]);
        ll[i] = f2bf(vv[i] - bf2f(hh[i]));
    }
    #pragma unroll
    for (int off = 32; off; off >>= 1) ssq += __shfl_xor(ssq, off);
    if (lane == 0) csq10[n] = 10.f * ssq;
    const int ks = d0 >> 5;
    const int q  = (d0 >> 3) & 3;
    const int s  = q ^ ((n >> 1) & 3);
    const size_t dst = (size_t)ks * CHUNK_USH + (n * 4 + s) * 8 + (d0 & 7);
    *(ushort4*)(bhi + dst) = make_ushort4(hh[0], hh[1], hh[2], hh[3]);
    *(ushort4*)(blo + dst) = make_ushort4(ll[0], ll[1], ll[2], ll[3]);
}

// ---- main: 256 blocks x 512 threads (8 waves = 4 M-groups x 2 N-halves) ----
union SmemU {
    struct { unsigned short Bh[2][HALF_USH], Bl[2][HALF_USH]; } k;  // 64 KB
    float lbuf[32 * 516];                                           // 66 KB overlay
};

__global__ __launch_bounds__(512, 2) void kmeans_mfma(
    const float* __restrict__ x, const unsigned short* __restrict__ bhi,
    const unsigned short* __restrict__ blo, const float* __restrict__ csq10,
    float* __restrict__ out) {
    __shared__ __align__(16) SmemU sm;
    __shared__ float red[2][2][BM];   // 2 KB

    const int tid  = threadIdx.x;
    const int w    = tid >> 6, lane = tid & 63;
    const int wm   = w >> 1, wn = w & 1;
    const int cc   = lane & 15, q = lane >> 4;
    const int row0 = blockIdx.x * BM;

    f32x4 acc[2][16];
    #pragma unroll
    for (int mt = 0; mt < 2; ++mt)
        #pragma unroll
        for (int t = 0; t < 16; ++t) acc[mt][t] = (f32x4){0.f, 0.f, 0.f, 0.f};

    // A: lane owns rows (row0 + wm*32 + mt*16 + cc), k-octet q*8 per chunk
    const float* xA0 = x + (size_t)(row0 + wm * 32 + cc) * DDIM + q * 8;
    const float* xA1 = xA0 + (size_t)16 * DDIM;
    // B fragment offset within a (staged or global) chunk table
    const int sF = q ^ ((cc >> 1) & 3);
    const int bF = (4 * cc + sF) * 8;
    // DMA: wave w stages staged-tiles st=2w,2w+1 (Bh+Bl): 4 ld16 ops.
    // staged st maps to table tile T(st)= st<8 ? st : st+8 (tiles 0-7,16-23).
    const int st0 = w * 2;
    const int T0  = (st0 < 8) ? st0 : st0 + 8;   // st0 even -> pair same half

    // ---- prologue: issue A(0), then DMA half-table chunk 0 -> buf 0 ----
    float4 c00 = *(const float4*)xA0;
    float4 c01 = *(const float4*)(xA0 + 4);
    float4 c10 = *(const float4*)xA1;
    float4 c11 = *(const float4*)(xA1 + 4);
    ld16(bhi + (size_t)T0 * 512 + lane * 8,       &sm.k.Bh[0][st0 * 512]);
    ld16(bhi + (size_t)(T0 + 1) * 512 + lane * 8, &sm.k.Bh[0][(st0 + 1) * 512]);
    ld16(blo + (size_t)T0 * 512 + lane * 8,       &sm.k.Bl[0][st0 * 512]);
    ld16(blo + (size_t)(T0 + 1) * 512 + lane * 8, &sm.k.Bl[0][(st0 + 1) * 512]);

    #pragma unroll
    for (int ks = 0; ks < KCH; ++ks) {
        const int pp = ks & 1;
        // convert A(ks): compiler-counted wait (DMA(ks)'s 4 ops younger)
        bf16x8 ah[2], al[2];
        {
            float v0[8] = {c00.x, c00.y, c00.z, c00.w, c01.x, c01.y, c01.z, c01.w};
            float v1[8] = {c10.x, c10.y, c10.z, c10.w, c11.x, c11.y, c11.z, c11.w};
            U8 H0, L0, H1, L1;
            #pragma unroll
            for (int e = 0; e < 8; ++e) {
                H0.u[e] = f2bf(v0[e]); L0.u[e] = f2bf(v0[e] - bf2f(H0.u[e]));
                H1.u[e] = f2bf(v1[e]); L1.u[e] = f2bf(v1[e] - bf2f(H1.u[e]));
            }
            ah[0] = H0.v; al[0] = L0.v; ah[1] = H1.v; al[1] = L1.v;
        }
        // issue A(ks+1) raw (stays in flight across the barrier; force-
        // drained at this chunk's g2 B-wait with ~600cyc of cover)
        float4 n00, n01, n10, n11;
        if (ks < KCH - 1) {
            const int kn = (ks + 1) * BK;
            n00 = *(const float4*)(xA0 + kn);
            n01 = *(const float4*)(xA0 + kn + 4);
            n10 = *(const float4*)(xA1 + kn);
            n11 = *(const float4*)(xA1 + kn + 4);
        }
        __builtin_amdgcn_sched_barrier(0);
        // counted wait: DMA(ks) (4 older) done; A(ks+1) (4 youngest) in flight
        if (ks < KCH - 1) {
            asm volatile("s_waitcnt vmcnt(4)" ::: "memory");
        } else {
            asm volatile("s_waitcnt vmcnt(0)" ::: "memory");
        }
        __builtin_amdgcn_s_barrier();
        __builtin_amdgcn_sched_barrier(0);
        // issue DMA(ks+1) half-table into the other slot (post-barrier safe)
        if (ks < KCH - 1) {
            const size_t cb = (size_t)(ks + 1) * CHUNK_USH;
            ld16(bhi + cb + T0 * 512 + lane * 8,       &sm.k.Bh[1 - pp][st0 * 512]);
            ld16(bhi + cb + (T0 + 1) * 512 + lane * 8, &sm.k.Bh[1 - pp][(st0 + 1) * 512]);
            ld16(blo + cb + T0 * 512 + lane * 8,       &sm.k.Bl[1 - pp][st0 * 512]);
            ld16(blo + cb + (T0 + 1) * 512 + lane * 8, &sm.k.Bl[1 - pp][(st0 + 1) * 512]);
        }
        // MFMA phase: groups 0-1 from LDS (staged idx st = wn*8+grp*4+tt),
        // groups 2-3 direct from global table (vmcnt pipe). Pass-major,
        // same tile/pass order as R20 -> bit-identical accumulation.
        #pragma unroll
        for (int grp = 0; grp < 4; ++grp) {
            bf16x8 bh[4], bl[4];
            if (grp < 2) {
                #pragma unroll
                for (int tt = 0; tt < 4; ++tt) {
                    const int so = (wn * 8 + grp * 4 + tt) * 512 + bF;
                    bh[tt] = *(const bf16x8*)&sm.k.Bh[pp][so];
                    bl[tt] = *(const bf16x8*)&sm.k.Bl[pp][so];
                }
            } else {
                const size_t go = (size_t)ks * CHUNK_USH + bF;
                #pragma unroll
                for (int tt = 0; tt < 4; ++tt) {
                    const int T = wn * 16 + grp * 4 + tt;
                    bh[tt] = *(const bf16x8*)(bhi + go + T * 512);
                    bl[tt] = *(const bf16x8*)(blo + go + T * 512);
                }
            }
            #pragma unroll
            for (int tt = 0; tt < 4; ++tt) {
                const int t = grp * 4 + tt;
                acc[0][t] = __builtin_amdgcn_mfma_f32_16x16x32_bf16(ah[0], bh[tt], acc[0][t], 0, 0, 0);
                acc[1][t] = __builtin_amdgcn_mfma_f32_16x16x32_bf16(ah[1], bh[tt], acc[1][t], 0, 0, 0);
            }
            #pragma unroll
            for (int tt = 0; tt < 4; ++tt) {
                const int t = grp * 4 + tt;
                acc[0][t] = __builtin_amdgcn_mfma_f32_16x16x32_bf16(ah[0], bl[tt], acc[0][t], 0, 0, 0);
                acc[1][t] = __builtin_amdgcn_mfma_f32_16x16x32_bf16(ah[1], bl[tt], acc[1][t], 0, 0, 0);
            }
            #pragma unroll
            for (int tt = 0; tt < 4; ++tt) {
                const int t = grp * 4 + tt;
                acc[0][t] = __builtin_amdgcn_mfma_f32_16x16x32_bf16(al[0], bh[tt], acc[0][t], 0, 0, 0);
                acc[1][t] = __builtin_amdgcn_mfma_f32_16x16x32_bf16(al[1], bh[tt], acc[1][t], 0, 0, 0);
            }
        }
        c00 = n00; c01 = n01; c10 = n10; c11 = n11;
    }

    // ---- softmax stats: reduce over t, then cc-lanes, then wn pair via LDS ----
    float csqv[16];
    #pragma unroll
    for (int t = 0; t < 16; ++t) csqv[t] = csq10[wn * 256 + t * 16 + cc];
    const int rb = wm * 32 + q * 4;   // + mt*16 + g
    float M[2][4], I[2][4];
    #pragma unroll
    for (int mt = 0; mt < 2; ++mt)
        #pragma unroll
        for (int g = 0; g < 4; ++g) {
            float pm = -1e30f;
            #pragma unroll
            for (int t = 0; t < 16; ++t) pm = fmaxf(pm, 20.f * acc[mt][t][g] - csqv[t]);
            #pragma unroll
            for (int off = 1; off < 16; off <<= 1) pm = fmaxf(pm, __shfl_xor(pm, off));
            if (cc == 0) red[0][wn][rb + mt * 16 + g] = pm;
            M[mt][g] = pm;
        }
    __syncthreads();
    #pragma unroll
    for (int mt = 0; mt < 2; ++mt)
        #pragma unroll
        for (int g = 0; g < 4; ++g) {
            M[mt][g] = fmaxf(M[mt][g], red[0][1 - wn][rb + mt * 16 + g]);
            float ps = 0.f;
            #pragma unroll
            for (int t = 0; t < 16; ++t) ps += __expf(20.f * acc[mt][t][g] - csqv[t] - M[mt][g]);
            #pragma unroll
            for (int off = 1; off < 16; off <<= 1) ps += __shfl_xor(ps, off);
            if (cc == 0) red[1][wn][rb + mt * 16 + g] = ps;
        }
    __syncthreads();
    #pragma unroll
    for (int mt = 0; mt < 2; ++mt)
        #pragma unroll
        for (int g = 0; g < 4; ++g)
            I[mt][g] = 1.f / (red[1][0][rb + mt * 16 + g] + red[1][1][rb + mt * 16 + g]);

    // ---- transpose epilogue: 4 passes of 32 rows through lbuf, dense stores ----
    #pragma unroll
    for (int p = 0; p < 4; ++p) {
        if (wm == p) {
            #pragma unroll
            for (int mt = 0; mt < 2; ++mt)
                #pragma unroll
                for (int g = 0; g < 4; ++g) {
                    const int   lr = mt * 16 + q * 4 + g;
                    const float mg = M[mt][g], ig = I[mt][g];
                    #pragma unroll
                    for (int t = 0; t < 16; ++t)
                        sm.lbuf[lr * 516 + wn * 256 + t * 16 + cc] =
                            __expf(20.f * acc[mt][t][g] - csqv[t] - mg) * ig;
                }
        }
        __syncthreads();
        #pragma unroll
        for (int j = 0; j < 8; ++j) {
            const int f    = j * 512 + tid;     // 0..4095 float4 slots
            const int lrow = f >> 7;            // 0..31
            const int c4   = f & 127;
            float4    v    = *(const float4*)&sm.lbuf[lrow * 516 + c4 * 4];
            *(float4*)(out + (size_t)(row0 + p * 32 + lrow) * KC + c4 * 4) = v;
        }
        __syncthreads();
    }
}

extern "C" void kernel_launch(void* const* d_in, const int* in_sizes, int n_in,
                              void* d_out, int out_size, void* d_ws, size_t ws_size,
                              hipStream_t stream) {
    const float* x   = (const float*)d_in[0];
    const float* c   = (const float*)d_in[1];
    float*       out = (float*)d_out;

    unsigned short* bhi   = (unsigned short*)d_ws;                 // 256 KB
    unsigned short* blo   = bhi + (size_t)KCH * CHUNK_USH;         // 256 KB
    float*          csq10 = (float*)(blo + (size_t)KCH * CHUNK_USH);  // 2 KB

    prep_c<<<KC, 64, 0, stream>>>(c, bhi, blo, csq10);
    kmeans_mfma<<<NROWS / BM, 512, 0, stream>>>(x, bhi, blo, csq10, out);
}